// Round 1
// baseline (316.722 us; speedup 1.0000x reference)
//
#include <hip/hip_runtime.h>

// Problem constants
#define DM    1024
#define NH    16
#define HD    64
#define SEQ   2048
#define BATCH 2
#define NQKV  3072          // 3*DM
#define MTOT  4096          // BATCH*SEQ

using half4 = __attribute__((ext_vector_type(4))) _Float16;
using half8 = __attribute__((ext_vector_type(8))) _Float16;
using f32x4 = __attribute__((ext_vector_type(4))) float;

typedef const __attribute__((address_space(1))) unsigned int* gp_t;
typedef __attribute__((address_space(3))) unsigned int* lp_t;

// async global->LDS, 16B per lane. LDS dest must be wave-uniform base + lane*16,
// which holds for all call sites below (lds offset == tid*16 + uniform).
__device__ __forceinline__ void gl2lds16(const void* g, void* l) {
    __builtin_amdgcn_global_load_lds((gp_t)g, (lp_t)l, 16, 0, 0);
}

__device__ __forceinline__ f32x4 fzero4() {
    f32x4 v; v[0] = 0.f; v[1] = 0.f; v[2] = 0.f; v[3] = 0.f; return v;
}

// ---------------------------------------------------------------- fp32 -> fp16
__global__ __launch_bounds__(256) void cvt_f32_f16(const float* __restrict__ in,
                                                   _Float16* __restrict__ out, int n4) {
    int i = blockIdx.x * 256 + threadIdx.x;
    if (i >= n4) return;
    float4 f = reinterpret_cast<const float4*>(in)[i];
    half4 h;
    h[0] = (_Float16)f.x; h[1] = (_Float16)f.y;
    h[2] = (_Float16)f.z; h[3] = (_Float16)f.w;
    reinterpret_cast<half4*>(out)[i] = h;
}

// ------------------------------------------------- NT GEMM (m97 structure)
// C[m][n] = sum_k A[m][k]*B[n][k] + bias[n].  128x128 tile, BK=64, 4 waves
// in 2x2, each wave 64x64 via 4x4 MFMA 16x16x32_f16 tiles.
template <bool OUT_F16>
__global__ __launch_bounds__(256) void gemm_nt(const _Float16* __restrict__ A,
                                               const _Float16* __restrict__ B,
                                               const float* __restrict__ bias,
                                               void* __restrict__ Cout,
                                               int M, int N, int K) {
    __shared__ _Float16 lA[128 * 64];
    __shared__ _Float16 lB[128 * 64];
    const int tid = threadIdx.x;
    const int m0 = blockIdx.y * 128, n0 = blockIdx.x * 128;
    const int wave = tid >> 6, lane = tid & 63, quad = lane >> 4, l15 = lane & 15;
    const int wm = (wave & 1) * 64, wn = (wave >> 1) * 64;

    f32x4 acc[4][4];
#pragma unroll
    for (int i = 0; i < 4; ++i)
#pragma unroll
        for (int j = 0; j < 4; ++j) acc[i][j] = fzero4();

    const _Float16* Ab = A + (long)(m0 + (tid >> 3)) * K + (tid & 7) * 8;
    const _Float16* Bb = B + (long)(n0 + (tid >> 3)) * K + (tid & 7) * 8;
    char* lAp = (char*)lA + tid * 16;
    char* lBp = (char*)lB + tid * 16;

    for (int kt = 0; kt < K; kt += 64) {
        __syncthreads();
#pragma unroll
        for (int j = 0; j < 4; ++j) {
            gl2lds16(Ab + (long)j * 32 * K + kt, lAp + j * 4096);
            gl2lds16(Bb + (long)j * 32 * K + kt, lBp + j * 4096);
        }
        __syncthreads();
#pragma unroll
        for (int ks = 0; ks < 2; ++ks) {
            half8 af[4], bfr[4];
#pragma unroll
            for (int t = 0; t < 4; ++t) {
                af[t]  = *(const half8*)(lA + (wm + t * 16 + l15) * 64 + ks * 32 + quad * 8);
                bfr[t] = *(const half8*)(lB + (wn + t * 16 + l15) * 64 + ks * 32 + quad * 8);
            }
#pragma unroll
            for (int mt = 0; mt < 4; ++mt)
#pragma unroll
                for (int nt = 0; nt < 4; ++nt)
                    acc[mt][nt] = __builtin_amdgcn_mfma_f32_16x16x32_f16(
                        af[mt], bfr[nt], acc[mt][nt], 0, 0, 0);
        }
    }

    float bs[4];
#pragma unroll
    for (int nt = 0; nt < 4; ++nt) bs[nt] = bias[n0 + wn + nt * 16 + l15];

#pragma unroll
    for (int mt = 0; mt < 4; ++mt) {
#pragma unroll
        for (int r = 0; r < 4; ++r) {
            const int m = m0 + wm + mt * 16 + quad * 4 + r;
#pragma unroll
            for (int nt = 0; nt < 4; ++nt) {
                const int n = n0 + wn + nt * 16 + l15;
                const float v = acc[mt][nt][r] + bs[nt];
                if constexpr (OUT_F16)
                    ((_Float16*)Cout)[(long)m * N + n] = (_Float16)v;
                else
                    ((float*)Cout)[(long)m * N + n] = v;
            }
        }
    }
}

// ------------------------------------- V repack: qkv[B,S,H*192] -> Vt[B,H,64,S]
__global__ __launch_bounds__(256) void repack_v(const _Float16* __restrict__ qkvh,
                                                _Float16* __restrict__ vt) {
    const int b = blockIdx.z, h = blockIdx.y, s0 = blockIdx.x * 32;
    const int d = threadIdx.x & 63, si = threadIdx.x >> 6;
    const _Float16* src = qkvh + (long)(b * SEQ + s0 + si * 8) * NQKV + h * 192 + 128 + d;
    half8 v;
#pragma unroll
    for (int i = 0; i < 8; ++i) v[i] = src[(long)i * NQKV];
    *(half8*)(vt + (long)((b * NH + h) * HD + d) * SEQ + s0 + si * 8) = v;
}

// ----------------------------------------------------- flash attention fwd
// Per block: (b, h, 128 q-rows). 4 waves, wave handles 32 q (2 col-tiles of
// S^T).  S^T = K·Q^T so S^T's C-layout (q = lane&15, key = quad*4+reg) IS the
// PV A-operand layout when two adjacent 16-key tiles are packed into one
// 16x16x32 fragment (slots 0-3 <- tile 2t, 4-7 <- tile 2t+1).  V fragments
// are read from Vt LDS with the matching key permutation (two 8B reads).
__global__ __launch_bounds__(256) void attn_flash(const _Float16* __restrict__ qkv,
                                                  const _Float16* __restrict__ vt,
                                                  _Float16* __restrict__ aout) {
    __shared__ _Float16 lQ[128 * 64];
    __shared__ _Float16 lK[128 * 64];
    __shared__ _Float16 lV[64 * 128];   // [d][key]  (V^T tile)
    const int b = blockIdx.z, h = blockIdx.y, q0 = blockIdx.x * 128;
    const int tid = threadIdx.x;
    const int wave = tid >> 6, lane = tid & 63, quad = lane >> 4, l15 = lane & 15;
    const float CS = 0.18033688011112042f;  // (1/8) * log2(e)

    // stage Q tile [128][64]
    const _Float16* qsrc = qkv + (long)(b * SEQ + q0 + (tid >> 3)) * NQKV + h * 192 + (tid & 7) * 8;
#pragma unroll
    for (int j = 0; j < 4; ++j)
        gl2lds16(qsrc + (long)j * 32 * NQKV, (char*)lQ + j * 4096 + tid * 16);
    __syncthreads();

    half8 qf[2][2];
#pragma unroll
    for (int qt = 0; qt < 2; ++qt)
#pragma unroll
        for (int ks = 0; ks < 2; ++ks)
            qf[qt][ks] = *(const half8*)(lQ + (wave * 32 + qt * 16 + l15) * 64 + ks * 32 + quad * 8);

    f32x4 O[2][4];
#pragma unroll
    for (int qt = 0; qt < 2; ++qt)
#pragma unroll
        for (int dt = 0; dt < 4; ++dt) O[qt][dt] = fzero4();
    float mst[2] = {-1e30f, -1e30f};
    float lst[2] = {0.f, 0.f};

    const _Float16* ksrc = qkv + (long)(b * SEQ + (tid >> 3)) * NQKV + h * 192 + 64 + (tid & 7) * 8;
    const _Float16* vsrc = vt + (long)((b * NH + h) * HD + (tid >> 4)) * SEQ + (tid & 15) * 8;

    for (int it = 0; it < 16; ++it) {
        const int s0 = it * 128;
        __syncthreads();
#pragma unroll
        for (int j = 0; j < 4; ++j) {
            gl2lds16(ksrc + (long)(s0 + j * 32) * NQKV, (char*)lK + j * 4096 + tid * 16);
            gl2lds16(vsrc + (long)j * 16 * SEQ + s0,    (char*)lV + j * 4096 + tid * 16);
        }
        __syncthreads();

        // S^T = K · Q^T   (raw scores, scale applied in exp)
        f32x4 st[2][8];
#pragma unroll
        for (int qt = 0; qt < 2; ++qt)
#pragma unroll
            for (int kt = 0; kt < 8; ++kt) st[qt][kt] = fzero4();
#pragma unroll
        for (int kt = 0; kt < 8; ++kt) {
#pragma unroll
            for (int ks = 0; ks < 2; ++ks) {
                half8 kf = *(const half8*)(lK + (kt * 16 + l15) * 64 + ks * 32 + quad * 8);
                st[0][kt] = __builtin_amdgcn_mfma_f32_16x16x32_f16(kf, qf[0][ks], st[0][kt], 0, 0, 0);
                st[1][kt] = __builtin_amdgcn_mfma_f32_16x16x32_f16(kf, qf[1][ks], st[1][kt], 0, 0, 0);
            }
        }

        // online softmax (per q-column = lane&15; reduce keys: in-lane + cross-quad)
        float alpha[2];
#pragma unroll
        for (int qt = 0; qt < 2; ++qt) {
            float mc = -1e30f;
#pragma unroll
            for (int kt = 0; kt < 8; ++kt) {
                f32x4 s = st[qt][kt];
                mc = fmaxf(mc, fmaxf(fmaxf(s[0], s[1]), fmaxf(s[2], s[3])));
            }
            mc = fmaxf(mc, __shfl_xor(mc, 16));
            mc = fmaxf(mc, __shfl_xor(mc, 32));
            mc *= CS;
            const float mn = fmaxf(mst[qt], mc);
            alpha[qt] = __builtin_amdgcn_exp2f(mst[qt] - mn);
            mst[qt] = mn;
            float rs = 0.f;
#pragma unroll
            for (int kt = 0; kt < 8; ++kt) {
#pragma unroll
                for (int r = 0; r < 4; ++r) {
                    const float p = __builtin_amdgcn_exp2f(st[qt][kt][r] * CS - mn);
                    st[qt][kt][r] = p;
                    rs += p;
                }
            }
            rs += __shfl_xor(rs, 16);
            rs += __shfl_xor(rs, 32);
            lst[qt] = lst[qt] * alpha[qt] + rs;
        }

        // rescale O rows (row index = quad*4+r; stats live in lanes 0..15 by column)
#pragma unroll
        for (int qt = 0; qt < 2; ++qt) {
#pragma unroll
            for (int r = 0; r < 4; ++r) {
                const float ar = __shfl(alpha[qt], quad * 4 + r);
#pragma unroll
                for (int dt = 0; dt < 4; ++dt) O[qt][dt][r] *= ar;
            }
        }

        // PV: A-frag = packed P (key perm: k=quad*8+j -> key 32t+quad*4+j (j<4),
        // 32t+16+quad*4+j-4 (j>=4)), B-frag = Vt with same perm.
#pragma unroll
        for (int t = 0; t < 4; ++t) {
            half8 pf0, pf1;
#pragma unroll
            for (int r = 0; r < 4; ++r) {
                pf0[r]     = (_Float16)st[0][2 * t][r];
                pf0[4 + r] = (_Float16)st[0][2 * t + 1][r];
                pf1[r]     = (_Float16)st[1][2 * t][r];
                pf1[4 + r] = (_Float16)st[1][2 * t + 1][r];
            }
#pragma unroll
            for (int dt = 0; dt < 4; ++dt) {
                const _Float16* vp = lV + (dt * 16 + l15) * 128 + t * 32 + quad * 4;
                half4 v0 = *(const half4*)(vp);
                half4 v1 = *(const half4*)(vp + 16);
                half8 vf = __builtin_shufflevector(v0, v1, 0, 1, 2, 3, 4, 5, 6, 7);
                O[0][dt] = __builtin_amdgcn_mfma_f32_16x16x32_f16(pf0, vf, O[0][dt], 0, 0, 0);
                O[1][dt] = __builtin_amdgcn_mfma_f32_16x16x32_f16(pf1, vf, O[1][dt], 0, 0, 0);
            }
        }
    }

    // epilogue: O / l, store f16 to attn-out [B*S, DM]
#pragma unroll
    for (int qt = 0; qt < 2; ++qt) {
        const float linv = 1.0f / lst[qt];
#pragma unroll
        for (int r = 0; r < 4; ++r) {
            const float lr = __shfl(linv, quad * 4 + r);
            const int row = b * SEQ + q0 + wave * 32 + qt * 16 + quad * 4 + r;
#pragma unroll
            for (int dt = 0; dt < 4; ++dt)
                aout[(long)row * DM + h * HD + dt * 16 + l15] =
                    (_Float16)(O[qt][dt][r] * lr);
        }
    }
}

// --------------------------------------------------------------------- launch
extern "C" void kernel_launch(void* const* d_in, const int* in_sizes, int n_in,
                              void* d_out, int out_size, void* d_ws, size_t ws_size,
                              hipStream_t stream) {
    const float* X    = (const float*)d_in[0];
    const float* Wqkv = (const float*)d_in[1];
    const float* bqkv = (const float*)d_in[2];
    const float* Wo   = (const float*)d_in[3];
    const float* bo   = (const float*)d_in[4];

    // workspace layout (56 MB total)
    char* ws = (char*)d_ws;
    _Float16* Xh   = (_Float16*)(ws);                        //  8 MB  [MTOT, DM]
    _Float16* Wqh  = (_Float16*)(ws + (size_t)8  * 1048576); //  6 MB  [NQKV, DM]
    _Float16* Woh  = (_Float16*)(ws + (size_t)14 * 1048576); //  2 MB  [DM, DM]
    _Float16* qkvh = (_Float16*)(ws + (size_t)16 * 1048576); // 24 MB  [MTOT, NQKV]
    _Float16* vth  = (_Float16*)(ws + (size_t)40 * 1048576); //  8 MB  [B, H, HD, SEQ]
    _Float16* atth = (_Float16*)(ws + (size_t)48 * 1048576); //  8 MB  [MTOT, DM]

    cvt_f32_f16<<<(MTOT * DM / 4 + 255) / 256, 256, 0, stream>>>(X, Xh, MTOT * DM / 4);
    cvt_f32_f16<<<(NQKV * DM / 4 + 255) / 256, 256, 0, stream>>>(Wqkv, Wqh, NQKV * DM / 4);
    cvt_f32_f16<<<(DM * DM / 4 + 255) / 256, 256, 0, stream>>>(Wo, Woh, DM * DM / 4);

    gemm_nt<true><<<dim3(NQKV / 128, MTOT / 128), 256, 0, stream>>>(
        Xh, Wqh, bqkv, qkvh, MTOT, NQKV, DM);

    repack_v<<<dim3(SEQ / 32, NH, BATCH), 256, 0, stream>>>(qkvh, vth);

    attn_flash<<<dim3(SEQ / 128, NH, BATCH), 256, 0, stream>>>(qkvh, vth, atth);

    gemm_nt<false><<<dim3(DM / 128, MTOT / 128), 256, 0, stream>>>(
        atth, Woh, bo, d_out, MTOT, DM, DM);
}

// Round 2
// 207.321 us; speedup vs baseline: 1.5277x; 1.5277x over previous
//
#include <hip/hip_runtime.h>

// Problem constants
#define DM    1024
#define NH    16
#define HD    64
#define SEQ   2048
#define BATCH 2
#define NQKV  3072          // 3*DM
#define MTOT  4096          // BATCH*SEQ

using half4 = __attribute__((ext_vector_type(4))) _Float16;
using half8 = __attribute__((ext_vector_type(8))) _Float16;
using f32x4 = __attribute__((ext_vector_type(4))) float;

typedef const __attribute__((address_space(1))) unsigned int* gp_t;
typedef __attribute__((address_space(3))) unsigned int* lp_t;

// async global->LDS, 16B per lane. LDS dest is wave-uniform base + lane*16
// (HW-pinned), so LDS swizzle is implemented by permuting the global SOURCE
// column per lane; readers apply the same XOR.
__device__ __forceinline__ void gl2lds16(const void* g, void* l) {
    __builtin_amdgcn_global_load_lds((gp_t)g, (lp_t)l, 16, 0, 0);
}

__device__ __forceinline__ f32x4 fzero4() {
    f32x4 v; v[0] = 0.f; v[1] = 0.f; v[2] = 0.f; v[3] = 0.f; return v;
}

// XOR-swizzled LDS indexing (units = halves, chunks = 16B = 8 halves).
// 64-half rows (8 chunks): bank-conflict-free reads for row-strided access.
__device__ __forceinline__ int sw8(int row, int col) {
    return (row << 6) | ((((col >> 3) ^ row) & 7) << 3) | (col & 7);
}
// 128-half rows (16 chunks).
__device__ __forceinline__ int sw16(int row, int col) {
    return (row << 7) | ((((col >> 3) ^ row) & 15) << 3) | (col & 7);
}

// ---------------------------------------------------------------- fp32 -> fp16
__global__ __launch_bounds__(256) void cvt_f32_f16(const float* __restrict__ in,
                                                   _Float16* __restrict__ out, int n4) {
    int i = blockIdx.x * 256 + threadIdx.x;
    if (i >= n4) return;
    float4 f = reinterpret_cast<const float4*>(in)[i];
    half4 h;
    h[0] = (_Float16)f.x; h[1] = (_Float16)f.y;
    h[2] = (_Float16)f.z; h[3] = (_Float16)f.w;
    reinterpret_cast<half4*>(out)[i] = h;
}

// ------------------------------------------------- NT GEMM (m97 structure)
// C[m][n] = sum_k A[m][k]*B[n][k] + bias[n].  128x128 tile, BK=64, 4 waves
// in 2x2, each wave 64x64 via 4x4 MFMA 16x16x32_f16 tiles. XOR-swizzled LDS.
template <bool OUT_F16>
__global__ __launch_bounds__(256) void gemm_nt(const _Float16* __restrict__ A,
                                               const _Float16* __restrict__ B,
                                               const float* __restrict__ bias,
                                               void* __restrict__ Cout,
                                               int M, int N, int K) {
    __shared__ _Float16 lA[128 * 64];
    __shared__ _Float16 lB[128 * 64];
    const int tid = threadIdx.x;
    const int m0 = blockIdx.y * 128, n0 = blockIdx.x * 128;
    const int wave = tid >> 6, lane = tid & 63, quad = lane >> 4, l15 = lane & 15;
    const int wm = (wave & 1) * 64, wn = (wave >> 1) * 64;

    f32x4 acc[4][4];
#pragma unroll
    for (int i = 0; i < 4; ++i)
#pragma unroll
        for (int j = 0; j < 4; ++j) acc[i][j] = fzero4();

    // staging: lane tid fills LDS chunk (tid&7) of row (tid>>3)+j*32; the
    // swizzle wants data chunk (tid&7)^(row&7) there -> permute source col.
    const int cperm = (((tid & 7) ^ (tid >> 3)) & 7) * 8;
    const _Float16* Ab = A + (long)(m0 + (tid >> 3)) * K + cperm;
    const _Float16* Bb = B + (long)(n0 + (tid >> 3)) * K + cperm;
    char* lAp = (char*)lA + tid * 16;
    char* lBp = (char*)lB + tid * 16;

    for (int kt = 0; kt < K; kt += 64) {
        __syncthreads();
#pragma unroll
        for (int j = 0; j < 4; ++j) {
            gl2lds16(Ab + (long)j * 32 * K + kt, lAp + j * 4096);
            gl2lds16(Bb + (long)j * 32 * K + kt, lBp + j * 4096);
        }
        __syncthreads();
#pragma unroll
        for (int ks = 0; ks < 2; ++ks) {
            half8 af[4], bfr[4];
#pragma unroll
            for (int t = 0; t < 4; ++t) {
                af[t]  = *(const half8*)(lA + sw8(wm + t * 16 + l15, ks * 32 + quad * 8));
                bfr[t] = *(const half8*)(lB + sw8(wn + t * 16 + l15, ks * 32 + quad * 8));
            }
#pragma unroll
            for (int mt = 0; mt < 4; ++mt)
#pragma unroll
                for (int nt = 0; nt < 4; ++nt)
                    acc[mt][nt] = __builtin_amdgcn_mfma_f32_16x16x32_f16(
                        af[mt], bfr[nt], acc[mt][nt], 0, 0, 0);
        }
    }

    float bs[4];
#pragma unroll
    for (int nt = 0; nt < 4; ++nt) bs[nt] = bias[n0 + wn + nt * 16 + l15];

#pragma unroll
    for (int mt = 0; mt < 4; ++mt) {
#pragma unroll
        for (int r = 0; r < 4; ++r) {
            const int m = m0 + wm + mt * 16 + quad * 4 + r;
#pragma unroll
            for (int nt = 0; nt < 4; ++nt) {
                const int n = n0 + wn + nt * 16 + l15;
                const float v = acc[mt][nt][r] + bs[nt];
                if constexpr (OUT_F16)
                    ((_Float16*)Cout)[(long)m * N + n] = (_Float16)v;
                else
                    ((float*)Cout)[(long)m * N + n] = v;
            }
        }
    }
}

// ------------------------------------- V repack: qkv[B,S,H*192] -> Vt[B,H,64,S]
__global__ __launch_bounds__(256) void repack_v(const _Float16* __restrict__ qkvh,
                                                _Float16* __restrict__ vt) {
    const int b = blockIdx.z, h = blockIdx.y, s0 = blockIdx.x * 32;
    const int d = threadIdx.x & 63, si = threadIdx.x >> 6;
    const _Float16* src = qkvh + (long)(b * SEQ + s0 + si * 8) * NQKV + h * 192 + 128 + d;
    half8 v;
#pragma unroll
    for (int i = 0; i < 8; ++i) v[i] = src[(long)i * NQKV];
    *(half8*)(vt + (long)((b * NH + h) * HD + d) * SEQ + s0 + si * 8) = v;
}

// ----------------------------------------------------- flash attention fwd
// Per block: (b, h, 128 q-rows). 4 waves, wave handles 32 q (2 col-tiles of
// S^T).  S^T = K·Q^T so S^T's C-layout (q = lane&15, key = quad*4+reg) IS the
// PV A-operand layout when two adjacent 16-key tiles are packed into one
// 16x16x32 fragment.  All LDS tiles XOR-swizzled (16B chunks) to kill the
// 16-way bank conflicts of the 128B-multiple row strides.
__global__ __launch_bounds__(256) void attn_flash(const _Float16* __restrict__ qkv,
                                                  const _Float16* __restrict__ vt,
                                                  _Float16* __restrict__ aout) {
    __shared__ _Float16 lQ[128 * 64];
    __shared__ _Float16 lK[128 * 64];
    __shared__ _Float16 lV[64 * 128];   // [d][key]  (V^T tile)
    const int b = blockIdx.z, h = blockIdx.y, q0 = blockIdx.x * 128;
    const int tid = threadIdx.x;
    const int wave = tid >> 6, lane = tid & 63, quad = lane >> 4, l15 = lane & 15;
    const float CS = 0.18033688011112042f;  // (1/8) * log2(e)

    const int cperm8  = (((tid & 7) ^ (tid >> 3)) & 7) * 8;    // for lQ/lK staging
    const int cperm16 = (((tid & 15) ^ (tid >> 4)) & 15) * 8;  // for lV staging

    // stage Q tile [128][64] (swizzled)
    const _Float16* qsrc = qkv + (long)(b * SEQ + q0 + (tid >> 3)) * NQKV + h * 192 + cperm8;
#pragma unroll
    for (int j = 0; j < 4; ++j)
        gl2lds16(qsrc + (long)j * 32 * NQKV, (char*)lQ + j * 4096 + tid * 16);
    __syncthreads();

    half8 qf[2][2];
#pragma unroll
    for (int qt = 0; qt < 2; ++qt)
#pragma unroll
        for (int ks = 0; ks < 2; ++ks)
            qf[qt][ks] = *(const half8*)(lQ + sw8(wave * 32 + qt * 16 + l15, ks * 32 + quad * 8));

    f32x4 O[2][4];
#pragma unroll
    for (int qt = 0; qt < 2; ++qt)
#pragma unroll
        for (int dt = 0; dt < 4; ++dt) O[qt][dt] = fzero4();
    float mst[2] = {-1e30f, -1e30f};
    float lst[2] = {0.f, 0.f};

    const _Float16* ksrc = qkv + (long)(b * SEQ + (tid >> 3)) * NQKV + h * 192 + 64 + cperm8;
    const _Float16* vsrc = vt + (long)((b * NH + h) * HD + (tid >> 4)) * SEQ + cperm16;

    for (int it = 0; it < 16; ++it) {
        const int s0 = it * 128;
        __syncthreads();
#pragma unroll
        for (int j = 0; j < 4; ++j) {
            gl2lds16(ksrc + (long)(s0 + j * 32) * NQKV, (char*)lK + j * 4096 + tid * 16);
            gl2lds16(vsrc + (long)j * 16 * SEQ + s0,    (char*)lV + j * 4096 + tid * 16);
        }
        __syncthreads();

        // S^T = K · Q^T   (raw scores, scale applied in exp)
        f32x4 st[2][8];
#pragma unroll
        for (int qt = 0; qt < 2; ++qt)
#pragma unroll
            for (int kt = 0; kt < 8; ++kt) st[qt][kt] = fzero4();
#pragma unroll
        for (int kt = 0; kt < 8; ++kt) {
#pragma unroll
            for (int ks = 0; ks < 2; ++ks) {
                half8 kf = *(const half8*)(lK + sw8(kt * 16 + l15, ks * 32 + quad * 8));
                st[0][kt] = __builtin_amdgcn_mfma_f32_16x16x32_f16(kf, qf[0][ks], st[0][kt], 0, 0, 0);
                st[1][kt] = __builtin_amdgcn_mfma_f32_16x16x32_f16(kf, qf[1][ks], st[1][kt], 0, 0, 0);
            }
        }

        // online softmax (per q-column = lane&15; reduce keys: in-lane + cross-quad)
        float alpha[2];
#pragma unroll
        for (int qt = 0; qt < 2; ++qt) {
            float mc = -1e30f;
#pragma unroll
            for (int kt = 0; kt < 8; ++kt) {
                f32x4 s = st[qt][kt];
                mc = fmaxf(mc, fmaxf(fmaxf(s[0], s[1]), fmaxf(s[2], s[3])));
            }
            mc = fmaxf(mc, __shfl_xor(mc, 16));
            mc = fmaxf(mc, __shfl_xor(mc, 32));
            mc *= CS;
            const float mn = fmaxf(mst[qt], mc);
            alpha[qt] = __builtin_amdgcn_exp2f(mst[qt] - mn);
            mst[qt] = mn;
            float rs = 0.f;
#pragma unroll
            for (int kt = 0; kt < 8; ++kt) {
#pragma unroll
                for (int r = 0; r < 4; ++r) {
                    const float p = __builtin_amdgcn_exp2f(st[qt][kt][r] * CS - mn);
                    st[qt][kt][r] = p;
                    rs += p;
                }
            }
            rs += __shfl_xor(rs, 16);
            rs += __shfl_xor(rs, 32);
            lst[qt] = lst[qt] * alpha[qt] + rs;
        }

        // rescale O rows (row index = quad*4+r; stats live per-column in lanes)
#pragma unroll
        for (int qt = 0; qt < 2; ++qt) {
#pragma unroll
            for (int r = 0; r < 4; ++r) {
                const float ar = __shfl(alpha[qt], quad * 4 + r);
#pragma unroll
                for (int dt = 0; dt < 4; ++dt) O[qt][dt][r] *= ar;
            }
        }

        // PV: A-frag = packed P (key perm: k=quad*8+j -> key 32t+quad*4+j (j<4),
        // 32t+16+quad*4+j-4 (j>=4)), B-frag = Vt with same perm (swizzled reads).
#pragma unroll
        for (int t = 0; t < 4; ++t) {
            half8 pf0, pf1;
#pragma unroll
            for (int r = 0; r < 4; ++r) {
                pf0[r]     = (_Float16)st[0][2 * t][r];
                pf0[4 + r] = (_Float16)st[0][2 * t + 1][r];
                pf1[r]     = (_Float16)st[1][2 * t][r];
                pf1[4 + r] = (_Float16)st[1][2 * t + 1][r];
            }
#pragma unroll
            for (int dt = 0; dt < 4; ++dt) {
                const int vrow = dt * 16 + l15;
                half4 v0 = *(const half4*)(lV + sw16(vrow, t * 32 + quad * 4));
                half4 v1 = *(const half4*)(lV + sw16(vrow, t * 32 + quad * 4 + 16));
                half8 vf = __builtin_shufflevector(v0, v1, 0, 1, 2, 3, 4, 5, 6, 7);
                O[0][dt] = __builtin_amdgcn_mfma_f32_16x16x32_f16(pf0, vf, O[0][dt], 0, 0, 0);
                O[1][dt] = __builtin_amdgcn_mfma_f32_16x16x32_f16(pf1, vf, O[1][dt], 0, 0, 0);
            }
        }
    }

    // epilogue: O / l, store f16 to attn-out [B*S, DM]
#pragma unroll
    for (int qt = 0; qt < 2; ++qt) {
        const float linv = 1.0f / lst[qt];
#pragma unroll
        for (int r = 0; r < 4; ++r) {
            const float lr = __shfl(linv, quad * 4 + r);
            const int row = b * SEQ + q0 + wave * 32 + qt * 16 + quad * 4 + r;
#pragma unroll
            for (int dt = 0; dt < 4; ++dt)
                aout[(long)row * DM + h * HD + dt * 16 + l15] =
                    (_Float16)(O[qt][dt][r] * lr);
        }
    }
}

// --------------------------------------------------------------------- launch
extern "C" void kernel_launch(void* const* d_in, const int* in_sizes, int n_in,
                              void* d_out, int out_size, void* d_ws, size_t ws_size,
                              hipStream_t stream) {
    const float* X    = (const float*)d_in[0];
    const float* Wqkv = (const float*)d_in[1];
    const float* bqkv = (const float*)d_in[2];
    const float* Wo   = (const float*)d_in[3];
    const float* bo   = (const float*)d_in[4];

    // workspace layout (56 MB total)
    char* ws = (char*)d_ws;
    _Float16* Xh   = (_Float16*)(ws);                        //  8 MB  [MTOT, DM]
    _Float16* Wqh  = (_Float16*)(ws + (size_t)8  * 1048576); //  6 MB  [NQKV, DM]
    _Float16* Woh  = (_Float16*)(ws + (size_t)14 * 1048576); //  2 MB  [DM, DM]
    _Float16* qkvh = (_Float16*)(ws + (size_t)16 * 1048576); // 24 MB  [MTOT, NQKV]
    _Float16* vth  = (_Float16*)(ws + (size_t)40 * 1048576); //  8 MB  [B, H, HD, SEQ]
    _Float16* atth = (_Float16*)(ws + (size_t)48 * 1048576); //  8 MB  [MTOT, DM]

    cvt_f32_f16<<<(MTOT * DM / 4 + 255) / 256, 256, 0, stream>>>(X, Xh, MTOT * DM / 4);
    cvt_f32_f16<<<(NQKV * DM / 4 + 255) / 256, 256, 0, stream>>>(Wqkv, Wqh, NQKV * DM / 4);
    cvt_f32_f16<<<(DM * DM / 4 + 255) / 256, 256, 0, stream>>>(Wo, Woh, DM * DM / 4);

    gemm_nt<true><<<dim3(NQKV / 128, MTOT / 128), 256, 0, stream>>>(
        Xh, Wqh, bqkv, qkvh, MTOT, NQKV, DM);

    repack_v<<<dim3(SEQ / 32, NH, BATCH), 256, 0, stream>>>(qkvh, vth);

    attn_flash<<<dim3(SEQ / 128, NH, BATCH), 256, 0, stream>>>(qkvh, vth, atth);

    gemm_nt<false><<<dim3(DM / 128, MTOT / 128), 256, 0, stream>>>(
        atth, Woh, bo, d_out, MTOT, DM, DM);
}